// Round 7
// baseline (178.750 us; speedup 1.0000x reference)
//
#include <hip/hip_runtime.h>

// Compact bilinear pooling via Gram GEMM + hash scatter (no FFT).
//   out[b, (h1[c1]+h2[c2]) % D] += s1[c1]*s2[c2] * G[b,c1,c2]
//
// R7: phase ablation + scatter fix. The ~60us floor survived load-side
// restructuring (R6) and atomic-merge removal (R5) -> suspect is the fused
// scatter phase. Split into:
//   A cbp_gram_store_kernel: MFMA Gram (s-folded fragments) -> G tiles in ws
//   B cbp_scatter_kernel:    G tile -> LDS buckets via unsafeAtomicAdd
//                            (native ds_add_f32; h1/h2 staged in LDS, no
//                            divergent global loads in the atomic chain)
//   C cbp_reduce_kernel:     sum 16 partials per (b,d)
// rocprof now prices each phase separately.

#define NB   32
#define HW   196
#define CC   512
#define DD   8192
#define NTHR 256
#define TILES_PER_B 16

typedef __attribute__((ext_vector_type(8)))  __bf16 bf8;
typedef __attribute__((ext_vector_type(16))) float  f32x16;

#define G_BYTES   ((size_t)NB * TILES_PER_B * 128 * 128 * 4)   // 33,554,432
#define PART_BYTES ((size_t)NB * TILES_PER_B * DD * 4)         // 16,777,216
#define NEED_SPLIT (G_BYTES + PART_BYTES)                      // 50,331,648
#define NEED_R5   PART_BYTES

// ---------- A: Gram MFMA, sign-folded, store G tiles ----------
__global__ __launch_bounds__(NTHR) void cbp_gram_store_kernel(
    const float* __restrict__ x1, const float* __restrict__ x2,
    const float* __restrict__ s1, const float* __restrict__ s2,
    float* __restrict__ G)
{
    const int bid  = blockIdx.x;
    const int b    = bid >> 4;
    const int t1   = (bid >> 2) & 3;
    const int t2   = bid & 3;
    const int tid  = threadIdx.x;
    const int wid  = tid >> 6;
    const int lane = tid & 63;
    const int wr   = wid >> 1;
    const int wc   = wid & 1;
    const int lo5  = lane & 31;
    const int hi   = lane >> 5;

    const int c1w = t1 * 128 + wr * 64;
    const int c2w = t2 * 128 + wc * 64;

    const float* A0 = x1 + (size_t)b * HW * CC + (c1w + lo5);
    const float* A1 = A0 + 32;
    const float* B0 = x2 + (size_t)b * HW * CC + (c2w + lo5);
    const float* B1 = B0 + 32;

    // fold signs into fragments (exact: s = +/-1)
    const float sA0 = s1[c1w + lo5],      sA1 = s1[c1w + 32 + lo5];
    const float sB0 = s2[c2w + lo5],      sB1 = s2[c2w + 32 + lo5];

    f32x16 acc00 = {}, acc01 = {}, acc10 = {}, acc11 = {};

    for (int ks = 0; ks < 12; ++ks) {
        const int kb = ks * 16 + hi * 8;
        bf8 a0, a1, b0v, b1v;
        #pragma unroll
        for (int j = 0; j < 8; ++j) {
            const size_t off = (size_t)(kb + j) * CC;
            a0[j]  = (__bf16)(A0[off] * sA0);
            a1[j]  = (__bf16)(A1[off] * sA1);
            b0v[j] = (__bf16)(B0[off] * sB0);
            b1v[j] = (__bf16)(B1[off] * sB1);
        }
        acc00 = __builtin_amdgcn_mfma_f32_32x32x16_bf16(a0, b0v, acc00, 0, 0, 0);
        acc01 = __builtin_amdgcn_mfma_f32_32x32x16_bf16(a0, b1v, acc01, 0, 0, 0);
        acc10 = __builtin_amdgcn_mfma_f32_32x32x16_bf16(a1, b0v, acc10, 0, 0, 0);
        acc11 = __builtin_amdgcn_mfma_f32_32x32x16_bf16(a1, b1v, acc11, 0, 0, 0);
    }
    {   // tail k = 192..195 (predicated)
        const int kb = 192 + hi * 8;
        bf8 a0, a1, b0v, b1v;
        #pragma unroll
        for (int j = 0; j < 8; ++j) {
            const int k = kb + j;
            const size_t off = (size_t)k * CC;
            const bool v = (k < HW);
            a0[j]  = (__bf16)(v ? A0[off] * sA0 : 0.0f);
            a1[j]  = (__bf16)(v ? A1[off] * sA1 : 0.0f);
            b0v[j] = (__bf16)(v ? B0[off] * sB0 : 0.0f);
            b1v[j] = (__bf16)(v ? B1[off] * sB1 : 0.0f);
        }
        acc00 = __builtin_amdgcn_mfma_f32_32x32x16_bf16(a0, b0v, acc00, 0, 0, 0);
        acc01 = __builtin_amdgcn_mfma_f32_32x32x16_bf16(a0, b1v, acc01, 0, 0, 0);
        acc10 = __builtin_amdgcn_mfma_f32_32x32x16_bf16(a1, b0v, acc10, 0, 0, 0);
        acc11 = __builtin_amdgcn_mfma_f32_32x32x16_bf16(a1, b1v, acc11, 0, 0, 0);
    }

    // store sign-folded G tile, row-major [c1l][c2l] 128x128.
    // C/D layout: c2l = wc*64 (+32*rt2) + lo5, c1l = wr*64 + rt*32 + (reg&3)+8*(reg>>2)+4*hi
    float* Gt = G + (size_t)bid * (128 * 128);
    #pragma unroll
    for (int rt = 0; rt < 2; ++rt) {
        const f32x16 accL = rt ? acc10 : acc00;   // c2 sub 0
        const f32x16 accR = rt ? acc11 : acc01;   // c2 sub 1
        #pragma unroll
        for (int reg = 0; reg < 16; ++reg) {
            const int c1l = wr * 64 + rt * 32 + (reg & 3) + 8 * (reg >> 2) + 4 * hi;
            Gt[c1l * 128 + wc * 64 + lo5]      = accL[reg];
            Gt[c1l * 128 + wc * 64 + 32 + lo5] = accR[reg];
        }
    }
}

// ---------- B: scatter G tile into hash buckets ----------
__global__ __launch_bounds__(NTHR) void cbp_scatter_kernel(
    const float* __restrict__ G,
    const int* __restrict__ h1, const int* __restrict__ h2,
    float* __restrict__ partials)
{
    __shared__ float accD[DD];     // 32 KB
    __shared__ int   h1t[128];
    __shared__ int   h2t[128];

    const int bid = blockIdx.x;
    const int t1  = (bid >> 2) & 3;
    const int t2  = bid & 3;
    const int tid = threadIdx.x;

    if (tid < 128)      h1t[tid]       = h1[t1 * 128 + tid];
    else if (tid < 256) h2t[tid - 128] = h2[t2 * 128 + (tid - 128)];
    for (int i = tid; i < DD; i += NTHR) accD[i] = 0.0f;
    __syncthreads();

    const float4* Gt = (const float4*)(G + (size_t)bid * (128 * 128));
    // 4096 float4s; thread handles 16, coalesced
    #pragma unroll
    for (int i = 0; i < 16; ++i) {
        const int idx  = tid + i * NTHR;       // float4 index
        const int c1l  = idx >> 5;
        const int c2l4 = (idx & 31) * 4;
        const float4 v = Gt[idx];
        const int hb = h1t[c1l];
        unsafeAtomicAdd(&accD[(hb + h2t[c2l4 + 0]) & (DD - 1)], v.x);
        unsafeAtomicAdd(&accD[(hb + h2t[c2l4 + 1]) & (DD - 1)], v.y);
        unsafeAtomicAdd(&accD[(hb + h2t[c2l4 + 2]) & (DD - 1)], v.z);
        unsafeAtomicAdd(&accD[(hb + h2t[c2l4 + 3]) & (DD - 1)], v.w);
    }
    __syncthreads();

    float4* dst = (float4*)(partials + (size_t)bid * DD);
    const float4* src = (const float4*)accD;
    #pragma unroll
    for (int i = 0; i < DD / 4 / NTHR; ++i)
        dst[tid + i * NTHR] = src[tid + i * NTHR];
}

// ---------- C: reduce 16 partials per (b,d) ----------
__global__ __launch_bounds__(NTHR) void cbp_reduce_kernel(
    const float* __restrict__ parts, float* __restrict__ out)
{
    const int b  = blockIdx.x >> 3;
    const int d0 = (blockIdx.x & 7) * 1024 + threadIdx.x * 4;
    const float* base = parts + (size_t)b * TILES_PER_B * DD + d0;
    float4 sum = {0.f, 0.f, 0.f, 0.f};
    #pragma unroll
    for (int t = 0; t < TILES_PER_B; ++t) {
        float4 v = *(const float4*)(base + (size_t)t * DD);
        sum.x += v.x; sum.y += v.y; sum.z += v.z; sum.w += v.w;
    }
    *(float4*)(out + (size_t)b * DD + d0) = sum;
}

// ---------- fallback: R5/R4 proven fused kernel ----------
__global__ __launch_bounds__(NTHR) void cbp_mfma_kernel(
    const float* __restrict__ x1, const float* __restrict__ x2,
    const float* __restrict__ s1, const float* __restrict__ s2,
    const int*   __restrict__ h1, const int*   __restrict__ h2,
    float* __restrict__ ws, float* __restrict__ out, int use_ws)
{
    __shared__ float accD[DD];
    const int bid  = blockIdx.x;
    const int b    = bid >> 4;
    const int t1   = (bid >> 2) & 3;
    const int t2   = bid & 3;
    const int tid  = threadIdx.x;
    const int wid  = tid >> 6;
    const int lane = tid & 63;
    const int wr   = wid >> 1;
    const int wc   = wid & 1;
    const int lo5  = lane & 31;
    const int hi   = lane >> 5;

    for (int i = tid; i < DD; i += NTHR) accD[i] = 0.0f;
    __syncthreads();

    const int c1w = t1 * 128 + wr * 64;
    const int c2w = t2 * 128 + wc * 64;
    const float* A0 = x1 + (size_t)b * HW * CC + (c1w + lo5);
    const float* A1 = A0 + 32;
    const float* B0 = x2 + (size_t)b * HW * CC + (c2w + lo5);
    const float* B1 = B0 + 32;

    f32x16 acc00 = {}, acc01 = {}, acc10 = {}, acc11 = {};
    for (int ks = 0; ks < 12; ++ks) {
        const int kb = ks * 16 + hi * 8;
        bf8 a0, a1, b0v, b1v;
        #pragma unroll
        for (int j = 0; j < 8; ++j) {
            const size_t off = (size_t)(kb + j) * CC;
            a0[j] = (__bf16)A0[off]; a1[j] = (__bf16)A1[off];
            b0v[j] = (__bf16)B0[off]; b1v[j] = (__bf16)B1[off];
        }
        acc00 = __builtin_amdgcn_mfma_f32_32x32x16_bf16(a0, b0v, acc00, 0, 0, 0);
        acc01 = __builtin_amdgcn_mfma_f32_32x32x16_bf16(a0, b1v, acc01, 0, 0, 0);
        acc10 = __builtin_amdgcn_mfma_f32_32x32x16_bf16(a1, b0v, acc10, 0, 0, 0);
        acc11 = __builtin_amdgcn_mfma_f32_32x32x16_bf16(a1, b1v, acc11, 0, 0, 0);
    }
    {
        const int kb = 192 + hi * 8;
        bf8 a0, a1, b0v, b1v;
        #pragma unroll
        for (int j = 0; j < 8; ++j) {
            const int k = kb + j;
            const size_t off = (size_t)k * CC;
            const bool v = (k < HW);
            a0[j]  = (__bf16)(v ? A0[off] : 0.0f);
            a1[j]  = (__bf16)(v ? A1[off] : 0.0f);
            b0v[j] = (__bf16)(v ? B0[off] : 0.0f);
            b1v[j] = (__bf16)(v ? B1[off] : 0.0f);
        }
        acc00 = __builtin_amdgcn_mfma_f32_32x32x16_bf16(a0, b0v, acc00, 0, 0, 0);
        acc01 = __builtin_amdgcn_mfma_f32_32x32x16_bf16(a0, b1v, acc01, 0, 0, 0);
        acc10 = __builtin_amdgcn_mfma_f32_32x32x16_bf16(a1, b0v, acc10, 0, 0, 0);
        acc11 = __builtin_amdgcn_mfma_f32_32x32x16_bf16(a1, b1v, acc11, 0, 0, 0);
    }

    const float s2v0 = s2[c2w + lo5];
    const float s2v1 = s2[c2w + 32 + lo5];
    const int   h2v0 = h2[c2w + lo5];
    const int   h2v1 = h2[c2w + 32 + lo5];
    #pragma unroll
    for (int rt = 0; rt < 2; ++rt) {
        const f32x16 accL = rt ? acc10 : acc00;
        const f32x16 accR = rt ? acc11 : acc01;
        #pragma unroll
        for (int reg = 0; reg < 16; ++reg) {
            const int c1 = c1w + rt * 32 + (reg & 3) + 8 * (reg >> 2) + 4 * hi;
            const float sv = s1[c1];
            const int   hv = h1[c1];
            unsafeAtomicAdd(&accD[(hv + h2v0) & (DD - 1)], sv * s2v0 * accL[reg]);
            unsafeAtomicAdd(&accD[(hv + h2v1) & (DD - 1)], sv * s2v1 * accR[reg]);
        }
    }
    __syncthreads();

    if (use_ws) {
        float4* dst = (float4*)(ws + (size_t)bid * DD);
        const float4* src = (const float4*)accD;
        #pragma unroll
        for (int i = 0; i < DD / 4 / NTHR; ++i)
            dst[tid + i * NTHR] = src[tid + i * NTHR];
    } else {
        float* ob = out + (size_t)b * DD;
        for (int i = tid; i < DD; i += NTHR)
            atomicAdd(&ob[i], accD[i]);
    }
}

extern "C" void kernel_launch(void* const* d_in, const int* in_sizes, int n_in,
                              void* d_out, int out_size, void* d_ws, size_t ws_size,
                              hipStream_t stream) {
    const float* x1 = (const float*)d_in[0];
    const float* x2 = (const float*)d_in[1];
    const float* s1 = (const float*)d_in[2];
    const float* s2 = (const float*)d_in[3];
    const int*   h1 = (const int*)d_in[4];
    const int*   h2 = (const int*)d_in[5];
    float* out = (float*)d_out;

    dim3 block(NTHR);
    if (ws_size >= NEED_SPLIT) {
        float* G     = (float*)d_ws;
        float* parts = (float*)((char*)d_ws + G_BYTES);
        cbp_gram_store_kernel<<<dim3(NB * TILES_PER_B), block, 0, stream>>>(
            x1, x2, s1, s2, G);
        cbp_scatter_kernel<<<dim3(NB * TILES_PER_B), block, 0, stream>>>(
            G, h1, h2, parts);
        cbp_reduce_kernel<<<dim3(NB * 8), block, 0, stream>>>(parts, out);
    } else if (ws_size >= NEED_R5) {
        float* parts = (float*)d_ws;
        cbp_mfma_kernel<<<dim3(NB * TILES_PER_B), block, 0, stream>>>(
            x1, x2, s1, s2, h1, h2, parts, out, 1);
        cbp_reduce_kernel<<<dim3(NB * 8), block, 0, stream>>>(parts, out);
    } else {
        hipMemsetAsync(out, 0, (size_t)out_size * sizeof(float), stream);
        cbp_mfma_kernel<<<dim3(NB * TILES_PER_B), block, 0, stream>>>(
            x1, x2, s1, s2, h1, h2, (float*)d_ws, out, 0);
    }
}

// Round 9
// 150.852 us; speedup vs baseline: 1.1849x; 1.1849x over previous
//
#include <hip/hip_runtime.h>

// Compact bilinear pooling via Gram GEMM + hash scatter (no FFT).
//   out[b, (h1[c1]+h2[c2]) % D] += s1[c1]*s2[c2] * G[b,c1,c2]
//
// R8 (resubmit; previous round hit a GPU-acquisition timeout, never ran):
// gram TLP/ILP fix. R7 ablation proved the ~70us floor is the Gram
// phase alone (no LDS/atomics) -> latency-bound at 2 waves/SIMD with a
// serial K chain. Now: 32x32 tile per wave (2048 blocks, ~20 waves/CU),
// two-phase K (7+7) with fragments register-resident (2 latency exposures),
// bf16 xT fragments (1 dwordx4 each, signs folded in transpose), XCD-chunk
// swizzle so each XCD's L2 holds its 4 batches' panels.
// ws: [G 33.5MB][parts 16.8MB (aliases dead xT)] = 50.33MB (proven in R7).

#define NB   32
#define HW   196
#define CC   512
#define DD   8192
#define KP   224
#define NTHR 256
#define TILES_PER_B 16

typedef __attribute__((ext_vector_type(8)))  __bf16 bf8;
typedef __attribute__((ext_vector_type(16))) float  f32x16;

#define G_BYTES    ((size_t)NB * TILES_PER_B * 128 * 128 * 4)  // 33,554,432
#define XT_ELEMS   ((size_t)NB * CC * KP)                      // 3,670,016
#define XT_BYTES   (XT_ELEMS * 2)                              // 7,340,032
#define PART_BYTES ((size_t)NB * TILES_PER_B * DD * 4)         // 16,777,216
#define NEED_SPLIT (G_BYTES + PART_BYTES)                      // 50,331,648
#define NEED_R5    PART_BYTES

// ---------- pass 0: x[b][k][c] fp32 -> xT[b][c][kp] bf16, signs folded ----
__global__ __launch_bounds__(NTHR) void cbp_transpose_kernel(
    const float* __restrict__ x1, const float* __restrict__ x2,
    const float* __restrict__ s1, const float* __restrict__ s2,
    __bf16* __restrict__ xT1, __bf16* __restrict__ xT2)
{
    __shared__ float T[64][65];
    const int bid = blockIdx.x;          // b*32 + ct*4 + kt
    const int b  = bid >> 5;
    const int ct = (bid >> 2) & 7;       // c tile (8 x 64)
    const int kt = bid & 3;              // k tile (4 x 64)
    const int tid = threadIdx.x;

    #pragma unroll
    for (int m = 0; m < 2; ++m) {
        const float* x   = m ? x2  : x1;
        const float* s   = m ? s2  : s1;
        __bf16*      xTo = m ? xT2 : xT1;

        #pragma unroll
        for (int p = 0; p < 4; ++p) {
            const int row  = p * 16 + (tid >> 4);      // k_local
            const int col4 = (tid & 15) * 4;           // c_local
            const int k = kt * 64 + row;
            float4 v = {0.f, 0.f, 0.f, 0.f};
            if (k < HW)
                v = *(const float4*)(x + ((size_t)(b * HW + k) * CC + ct * 64 + col4));
            T[col4 + 0][row] = v.x;
            T[col4 + 1][row] = v.y;
            T[col4 + 2][row] = v.z;
            T[col4 + 3][row] = v.w;
        }
        __syncthreads();

        const int c_l = tid >> 2;        // 0..63
        const int seg = tid & 3;         // 16 kp per seg
        const int kp0 = kt * 64 + seg * 16;
        if (kp0 < KP) {
            const float sv = s[ct * 64 + c_l];
            const size_t dstc = (size_t)(b * CC + ct * 64 + c_l) * KP;
            #pragma unroll
            for (int i2 = 0; i2 < 2; ++i2) {
                bf8 v;
                #pragma unroll
                for (int i = 0; i < 8; ++i)
                    v[i] = (__bf16)(T[c_l][seg * 16 + i2 * 8 + i] * sv);
                *(bf8*)(xTo + dstc + kp0 + i2 * 8) = v;
            }
        }
        __syncthreads();
    }
}

// ---------- pass 1: Gram MFMA, 32x32 tile per wave ----------
__global__ __launch_bounds__(NTHR, 5) void cbp_gram2_kernel(
    const __bf16* __restrict__ xT1, const __bf16* __restrict__ xT2,
    float* __restrict__ G)
{
    const int bid  = blockIdx.x;                   // 0..2047
    const int swz  = (bid & 7) * 256 + (bid >> 3); // XCD chunking (bijective)
    const int tid  = threadIdx.x;
    const int wid  = tid >> 6;
    const int lane = tid & 63;
    const int lo5  = lane & 31;
    const int hi   = lane >> 5;

    const int t  = swz * 4 + wid;     // 32x32 tile id, 0..8191
    const int b  = t >> 8;
    const int r  = t & 255;
    const int u1 = r >> 4;            // c1 32-tile 0..15
    const int u2 = r & 15;            // c2 32-tile 0..15

    const __bf16* A  = xT1 + ((size_t)(b * CC + u1 * 32 + lo5) * KP + hi * 8);
    const __bf16* Bp = xT2 + ((size_t)(b * CC + u2 * 32 + lo5) * KP + hi * 8);

    f32x16 acc = {};
    bf8 Af[7], Bf[7];

    // phase 1: steps 0..6 fully register-resident
    #pragma unroll
    for (int s = 0; s < 7; ++s) {
        Af[s] = *(const bf8*)(A  + s * 16);
        Bf[s] = *(const bf8*)(Bp + s * 16);
    }
    #pragma unroll
    for (int s = 0; s < 7; ++s)
        acc = __builtin_amdgcn_mfma_f32_32x32x16_bf16(Af[s], Bf[s], acc, 0, 0, 0);

    // phase 2: steps 7..13
    #pragma unroll
    for (int s = 0; s < 7; ++s) {
        Af[s] = *(const bf8*)(A  + (7 + s) * 16);
        Bf[s] = *(const bf8*)(Bp + (7 + s) * 16);
    }
    #pragma unroll
    for (int s = 0; s < 7; ++s)
        acc = __builtin_amdgcn_mfma_f32_32x32x16_bf16(Af[s], Bf[s], acc, 0, 0, 0);

    // store into the 128x128-tile G layout used by the scatter kernel.
    // C/D: col = lane&31, row = (reg&3)+8*(reg>>2)+4*(lane>>5)
    float* Gt = G + (size_t)(b * 16 + (u1 >> 2) * 4 + (u2 >> 2)) * (128 * 128);
    const int c2l = (u2 & 3) * 32 + lo5;
    #pragma unroll
    for (int reg = 0; reg < 16; ++reg) {
        const int c1l = (u1 & 3) * 32 + (reg & 3) + 8 * (reg >> 2) + 4 * hi;
        Gt[c1l * 128 + c2l] = acc[reg];
    }
}

// ---------- pass 2: scatter G tile into hash buckets ----------
__global__ __launch_bounds__(NTHR) void cbp_scatter_kernel(
    const float* __restrict__ G,
    const int* __restrict__ h1, const int* __restrict__ h2,
    float* __restrict__ partials)
{
    __shared__ float accD[DD];     // 32 KB
    __shared__ int   h1t[128];
    __shared__ int   h2t[128];

    const int bid = blockIdx.x;
    const int t1  = (bid >> 2) & 3;
    const int t2  = bid & 3;
    const int tid = threadIdx.x;

    if (tid < 128)      h1t[tid]       = h1[t1 * 128 + tid];
    else if (tid < 256) h2t[tid - 128] = h2[t2 * 128 + (tid - 128)];
    for (int i = tid; i < DD; i += NTHR) accD[i] = 0.0f;
    __syncthreads();

    const float4* Gt = (const float4*)(G + (size_t)bid * (128 * 128));
    #pragma unroll
    for (int i = 0; i < 16; ++i) {
        const int idx  = tid + i * NTHR;       // float4 index
        const int c1l  = idx >> 5;
        const int c2l4 = (idx & 31) * 4;
        const float4 v = Gt[idx];
        const int hb = h1t[c1l];
        unsafeAtomicAdd(&accD[(hb + h2t[c2l4 + 0]) & (DD - 1)], v.x);
        unsafeAtomicAdd(&accD[(hb + h2t[c2l4 + 1]) & (DD - 1)], v.y);
        unsafeAtomicAdd(&accD[(hb + h2t[c2l4 + 2]) & (DD - 1)], v.z);
        unsafeAtomicAdd(&accD[(hb + h2t[c2l4 + 3]) & (DD - 1)], v.w);
    }
    __syncthreads();

    float4* dst = (float4*)(partials + (size_t)bid * DD);
    const float4* src = (const float4*)accD;
    #pragma unroll
    for (int i = 0; i < DD / 4 / NTHR; ++i)
        dst[tid + i * NTHR] = src[tid + i * NTHR];
}

// ---------- pass 3: reduce 16 partials per (b,d) ----------
__global__ __launch_bounds__(NTHR) void cbp_reduce_kernel(
    const float* __restrict__ parts, float* __restrict__ out)
{
    const int b  = blockIdx.x >> 3;
    const int d0 = (blockIdx.x & 7) * 1024 + threadIdx.x * 4;
    const float* base = parts + (size_t)b * TILES_PER_B * DD + d0;
    float4 sum = {0.f, 0.f, 0.f, 0.f};
    #pragma unroll
    for (int t = 0; t < TILES_PER_B; ++t) {
        float4 v = *(const float4*)(base + (size_t)t * DD);
        sum.x += v.x; sum.y += v.y; sum.z += v.z; sum.w += v.w;
    }
    *(float4*)(out + (size_t)b * DD + d0) = sum;
}

// ---------- fallback: R5/R4 proven fused kernel ----------
__global__ __launch_bounds__(NTHR) void cbp_mfma_kernel(
    const float* __restrict__ x1, const float* __restrict__ x2,
    const float* __restrict__ s1, const float* __restrict__ s2,
    const int*   __restrict__ h1, const int*   __restrict__ h2,
    float* __restrict__ ws, float* __restrict__ out, int use_ws)
{
    __shared__ float accD[DD];
    const int bid  = blockIdx.x;
    const int b    = bid >> 4;
    const int t1   = (bid >> 2) & 3;
    const int t2   = bid & 3;
    const int tid  = threadIdx.x;
    const int wid  = tid >> 6;
    const int lane = tid & 63;
    const int wr   = wid >> 1;
    const int wc   = wid & 1;
    const int lo5  = lane & 31;
    const int hi   = lane >> 5;

    for (int i = tid; i < DD; i += NTHR) accD[i] = 0.0f;
    __syncthreads();

    const int c1w = t1 * 128 + wr * 64;
    const int c2w = t2 * 128 + wc * 64;
    const float* A0 = x1 + (size_t)b * HW * CC + (c1w + lo5);
    const float* A1 = A0 + 32;
    const float* B0 = x2 + (size_t)b * HW * CC + (c2w + lo5);
    const float* B1 = B0 + 32;

    f32x16 acc00 = {}, acc01 = {}, acc10 = {}, acc11 = {};
    for (int ks = 0; ks < 12; ++ks) {
        const int kb = ks * 16 + hi * 8;
        bf8 a0, a1, b0v, b1v;
        #pragma unroll
        for (int j = 0; j < 8; ++j) {
            const size_t off = (size_t)(kb + j) * CC;
            a0[j] = (__bf16)A0[off]; a1[j] = (__bf16)A1[off];
            b0v[j] = (__bf16)B0[off]; b1v[j] = (__bf16)B1[off];
        }
        acc00 = __builtin_amdgcn_mfma_f32_32x32x16_bf16(a0, b0v, acc00, 0, 0, 0);
        acc01 = __builtin_amdgcn_mfma_f32_32x32x16_bf16(a0, b1v, acc01, 0, 0, 0);
        acc10 = __builtin_amdgcn_mfma_f32_32x32x16_bf16(a1, b0v, acc10, 0, 0, 0);
        acc11 = __builtin_amdgcn_mfma_f32_32x32x16_bf16(a1, b1v, acc11, 0, 0, 0);
    }
    {
        const int kb = 192 + hi * 8;
        bf8 a0, a1, b0v, b1v;
        #pragma unroll
        for (int j = 0; j < 8; ++j) {
            const int k = kb + j;
            const size_t off = (size_t)k * CC;
            const bool v = (k < HW);
            a0[j]  = (__bf16)(v ? A0[off] : 0.0f);
            a1[j]  = (__bf16)(v ? A1[off] : 0.0f);
            b0v[j] = (__bf16)(v ? B0[off] : 0.0f);
            b1v[j] = (__bf16)(v ? B1[off] : 0.0f);
        }
        acc00 = __builtin_amdgcn_mfma_f32_32x32x16_bf16(a0, b0v, acc00, 0, 0, 0);
        acc01 = __builtin_amdgcn_mfma_f32_32x32x16_bf16(a0, b1v, acc01, 0, 0, 0);
        acc10 = __builtin_amdgcn_mfma_f32_32x32x16_bf16(a1, b0v, acc10, 0, 0, 0);
        acc11 = __builtin_amdgcn_mfma_f32_32x32x16_bf16(a1, b1v, acc11, 0, 0, 0);
    }

    const float s2v0 = s2[c2w + lo5];
    const float s2v1 = s2[c2w + 32 + lo5];
    const int   h2v0 = h2[c2w + lo5];
    const int   h2v1 = h2[c2w + 32 + lo5];
    #pragma unroll
    for (int rt = 0; rt < 2; ++rt) {
        const f32x16 accL = rt ? acc10 : acc00;
        const f32x16 accR = rt ? acc11 : acc01;
        #pragma unroll
        for (int reg = 0; reg < 16; ++reg) {
            const int c1 = c1w + rt * 32 + (reg & 3) + 8 * (reg >> 2) + 4 * hi;
            const float sv = s1[c1];
            const int   hv = h1[c1];
            unsafeAtomicAdd(&accD[(hv + h2v0) & (DD - 1)], sv * s2v0 * accL[reg]);
            unsafeAtomicAdd(&accD[(hv + h2v1) & (DD - 1)], sv * s2v1 * accR[reg]);
        }
    }
    __syncthreads();

    if (use_ws) {
        float4* dst = (float4*)(ws + (size_t)bid * DD);
        const float4* src = (const float4*)accD;
        #pragma unroll
        for (int i = 0; i < DD / 4 / NTHR; ++i)
            dst[tid + i * NTHR] = src[tid + i * NTHR];
    } else {
        float* ob = out + (size_t)b * DD;
        for (int i = tid; i < DD; i += NTHR)
            atomicAdd(&ob[i], accD[i]);
    }
}

extern "C" void kernel_launch(void* const* d_in, const int* in_sizes, int n_in,
                              void* d_out, int out_size, void* d_ws, size_t ws_size,
                              hipStream_t stream) {
    const float* x1 = (const float*)d_in[0];
    const float* x2 = (const float*)d_in[1];
    const float* s1 = (const float*)d_in[2];
    const float* s2 = (const float*)d_in[3];
    const int*   h1 = (const int*)d_in[4];
    const int*   h2 = (const int*)d_in[5];
    float* out = (float*)d_out;

    dim3 block(NTHR);
    if (ws_size >= NEED_SPLIT) {
        float*  G     = (float*)d_ws;
        // xT lives where parts will go later: dead before scatter writes parts
        __bf16* xT1   = (__bf16*)((char*)d_ws + G_BYTES);
        __bf16* xT2   = xT1 + XT_ELEMS;
        float*  parts = (float*)((char*)d_ws + G_BYTES);
        cbp_transpose_kernel<<<dim3(NB * 32), block, 0, stream>>>(
            x1, x2, s1, s2, xT1, xT2);
        cbp_gram2_kernel<<<dim3(2048), block, 0, stream>>>(xT1, xT2, G);
        cbp_scatter_kernel<<<dim3(NB * TILES_PER_B), block, 0, stream>>>(
            G, h1, h2, parts);
        cbp_reduce_kernel<<<dim3(NB * 8), block, 0, stream>>>(parts, out);
    } else if (ws_size >= NEED_R5) {
        float* parts = (float*)d_ws;
        cbp_mfma_kernel<<<dim3(NB * TILES_PER_B), block, 0, stream>>>(
            x1, x2, s1, s2, h1, h2, parts, out, 1);
        cbp_reduce_kernel<<<dim3(NB * 8), block, 0, stream>>>(parts, out);
    } else {
        hipMemsetAsync(out, 0, (size_t)out_size * sizeof(float), stream);
        cbp_mfma_kernel<<<dim3(NB * TILES_PER_B), block, 0, stream>>>(
            x1, x2, s1, s2, h1, h2, (float*)d_ws, out, 0);
    }
}

// Round 11
// 141.215 us; speedup vs baseline: 1.2658x; 1.0682x over previous
//
#include <hip/hip_runtime.h>

// Compact bilinear pooling via Gram GEMM + hash scatter (no FFT).
//   out[b, (h1[c1]+h2[c2]) % D] += s1[c1]*s2[c2] * G[b,c1,c2]
//
// R10 (resubmit; previous round hit a GPU-acquisition timeout, never ran):
// fuse scatter into gram epilogue. R9 showed the wall moved to the
// standalone scatter kernel (48us: G HBM round-trip + latency-serialized
// load->atomic chain). R5-vs-R7 proved fused scatter is ~free (LDS atomics
// overlap other waves' stalls). One block = one 128x128 tile (512 blocks,
// XCD swizzle), 4 waves x 64x64, K register-resident in two 7-step phases
// (R8's proven TLP/ILP fix), epilogue ds_add -> accD -> parts. G never
// touches memory (-67MB traffic, -1 dispatch).

#define NB   32
#define HW   196
#define CC   512
#define DD   8192
#define KP   224
#define NTHR 256
#define TILES_PER_B 16

typedef __attribute__((ext_vector_type(8)))  __bf16 bf8;
typedef __attribute__((ext_vector_type(16))) float  f32x16;

#define XT_ELEMS   ((size_t)NB * CC * KP)                      // 3,670,016
#define XT_BYTES   (XT_ELEMS * 2)                              // 7,340,032
#define PART_BYTES ((size_t)NB * TILES_PER_B * DD * 4)         // 16,777,216
#define NEED_FUSED (2 * XT_BYTES + PART_BYTES)                 // 31,457,280
#define NEED_R5    PART_BYTES

// ---------- pass 0: x[b][k][c] fp32 -> xT[b][c][kp] bf16, signs folded ----
__global__ __launch_bounds__(NTHR) void cbp_transpose_kernel(
    const float* __restrict__ x1, const float* __restrict__ x2,
    const float* __restrict__ s1, const float* __restrict__ s2,
    __bf16* __restrict__ xT1, __bf16* __restrict__ xT2)
{
    __shared__ float T[64][65];
    const int bid = blockIdx.x;          // b*32 + ct*4 + kt
    const int b  = bid >> 5;
    const int ct = (bid >> 2) & 7;       // c tile (8 x 64)
    const int kt = bid & 3;              // k tile (4 x 64)
    const int tid = threadIdx.x;

    #pragma unroll
    for (int m = 0; m < 2; ++m) {
        const float* x   = m ? x2  : x1;
        const float* s   = m ? s2  : s1;
        __bf16*      xTo = m ? xT2 : xT1;

        #pragma unroll
        for (int p = 0; p < 4; ++p) {
            const int row  = p * 16 + (tid >> 4);      // k_local
            const int col4 = (tid & 15) * 4;           // c_local
            const int k = kt * 64 + row;
            float4 v = {0.f, 0.f, 0.f, 0.f};
            if (k < HW)
                v = *(const float4*)(x + ((size_t)(b * HW + k) * CC + ct * 64 + col4));
            T[col4 + 0][row] = v.x;
            T[col4 + 1][row] = v.y;
            T[col4 + 2][row] = v.z;
            T[col4 + 3][row] = v.w;
        }
        __syncthreads();

        const int c_l = tid >> 2;        // 0..63
        const int seg = tid & 3;         // 16 kp per seg
        const int kp0 = kt * 64 + seg * 16;
        if (kp0 < KP) {
            const float sv = s[ct * 64 + c_l];
            const size_t dstc = (size_t)(b * CC + ct * 64 + c_l) * KP;
            #pragma unroll
            for (int i2 = 0; i2 < 2; ++i2) {
                bf8 v;
                #pragma unroll
                for (int i = 0; i < 8; ++i)
                    v[i] = (__bf16)(T[c_l][seg * 16 + i2 * 8 + i] * sv);
                *(bf8*)(xTo + dstc + kp0 + i2 * 8) = v;
            }
        }
        __syncthreads();
    }
}

// ---------- pass 1: fused Gram MFMA + hash scatter ----------
__global__ __launch_bounds__(NTHR, 2) void cbp_gram_scatter_kernel(
    const __bf16* __restrict__ xT1, const __bf16* __restrict__ xT2,
    const int* __restrict__ h1, const int* __restrict__ h2,
    float* __restrict__ partials)
{
    __shared__ float accD[DD];     // 32 KB
    __shared__ int   h1t[128];
    __shared__ int   h2t[128];

    const int bid0 = blockIdx.x;                     // 0..511
    const int bid  = (bid0 & 7) * 64 + (bid0 >> 3);  // XCD chunking (bijective)
    const int b    = bid >> 4;
    const int t1   = (bid >> 2) & 3;
    const int t2   = bid & 3;
    const int tid  = threadIdx.x;
    const int wid  = tid >> 6;
    const int lane = tid & 63;
    const int wr   = wid >> 1;      // 2x2 wave grid, 64x64 each
    const int wc   = wid & 1;
    const int lo5  = lane & 31;
    const int hi   = lane >> 5;

    if (tid < 128)      h1t[tid]       = h1[t1 * 128 + tid];
    else if (tid < 256) h2t[tid - 128] = h2[t2 * 128 + (tid - 128)];
    for (int i = tid; i < DD; i += NTHR) accD[i] = 0.0f;

    // fragment base pointers (signs already folded into xT)
    const __bf16* A0 = xT1 + ((size_t)(b * CC + t1 * 128 + wr * 64 + lo5) * KP + hi * 8);
    const __bf16* A1 = A0 + (size_t)32 * KP;
    const __bf16* B0 = xT2 + ((size_t)(b * CC + t2 * 128 + wc * 64 + lo5) * KP + hi * 8);
    const __bf16* B1 = B0 + (size_t)32 * KP;

    f32x16 acc00 = {}, acc01 = {}, acc10 = {}, acc11 = {};

    // two K-halves, all 28 fragments register-resident per half
    #pragma unroll
    for (int half = 0; half < 2; ++half) {
        const int kof = half * 7 * 16;
        bf8 Af0[7], Af1[7], Bf0[7], Bf1[7];
        #pragma unroll
        for (int s = 0; s < 7; ++s) {
            Af0[s] = *(const bf8*)(A0 + kof + s * 16);
            Af1[s] = *(const bf8*)(A1 + kof + s * 16);
            Bf0[s] = *(const bf8*)(B0 + kof + s * 16);
            Bf1[s] = *(const bf8*)(B1 + kof + s * 16);
        }
        #pragma unroll
        for (int s = 0; s < 7; ++s) {
            acc00 = __builtin_amdgcn_mfma_f32_32x32x16_bf16(Af0[s], Bf0[s], acc00, 0, 0, 0);
            acc01 = __builtin_amdgcn_mfma_f32_32x32x16_bf16(Af0[s], Bf1[s], acc01, 0, 0, 0);
            acc10 = __builtin_amdgcn_mfma_f32_32x32x16_bf16(Af1[s], Bf0[s], acc10, 0, 0, 0);
            acc11 = __builtin_amdgcn_mfma_f32_32x32x16_bf16(Af1[s], Bf1[s], acc11, 0, 0, 0);
        }
    }

    __syncthreads();   // accD zero-init complete before any atomic

    // scatter 64 register values/thread into buckets.
    // C/D: col = lane&31, row = (reg&3)+8*(reg>>2)+4*(lane>>5)
    const int h2v0 = h2t[wc * 64 + lo5];
    const int h2v1 = h2t[wc * 64 + 32 + lo5];
    #pragma unroll
    for (int rt = 0; rt < 2; ++rt) {
        const f32x16 accL = rt ? acc10 : acc00;   // c2 sub 0
        const f32x16 accR = rt ? acc11 : acc01;   // c2 sub 1
        #pragma unroll
        for (int reg = 0; reg < 16; ++reg) {
            const int c1l = wr * 64 + rt * 32 + (reg & 3) + 8 * (reg >> 2) + 4 * hi;
            const int hb  = h1t[c1l];
            unsafeAtomicAdd(&accD[(hb + h2v0) & (DD - 1)], accL[reg]);
            unsafeAtomicAdd(&accD[(hb + h2v1) & (DD - 1)], accR[reg]);
        }
    }
    __syncthreads();

    float4* dst = (float4*)(partials + (size_t)bid * DD);
    const float4* src = (const float4*)accD;
    #pragma unroll
    for (int i = 0; i < DD / 4 / NTHR; ++i)
        dst[tid + i * NTHR] = src[tid + i * NTHR];
}

// ---------- pass 2: reduce 16 partials per (b,d) ----------
__global__ __launch_bounds__(NTHR) void cbp_reduce_kernel(
    const float* __restrict__ parts, float* __restrict__ out)
{
    const int b  = blockIdx.x >> 3;
    const int d0 = (blockIdx.x & 7) * 1024 + threadIdx.x * 4;
    const float* base = parts + (size_t)b * TILES_PER_B * DD + d0;
    float4 sum = {0.f, 0.f, 0.f, 0.f};
    #pragma unroll
    for (int t = 0; t < TILES_PER_B; ++t) {
        float4 v = *(const float4*)(base + (size_t)t * DD);
        sum.x += v.x; sum.y += v.y; sum.z += v.z; sum.w += v.w;
    }
    *(float4*)(out + (size_t)b * DD + d0) = sum;
}

// ---------- fallback: R5/R4 proven fused kernel (fp32 inputs direct) ----------
__global__ __launch_bounds__(NTHR) void cbp_mfma_kernel(
    const float* __restrict__ x1, const float* __restrict__ x2,
    const float* __restrict__ s1, const float* __restrict__ s2,
    const int*   __restrict__ h1, const int*   __restrict__ h2,
    float* __restrict__ ws, float* __restrict__ out, int use_ws)
{
    __shared__ float accD[DD];
    const int bid  = blockIdx.x;
    const int b    = bid >> 4;
    const int t1   = (bid >> 2) & 3;
    const int t2   = bid & 3;
    const int tid  = threadIdx.x;
    const int wid  = tid >> 6;
    const int lane = tid & 63;
    const int wr   = wid >> 1;
    const int wc   = wid & 1;
    const int lo5  = lane & 31;
    const int hi   = lane >> 5;

    for (int i = tid; i < DD; i += NTHR) accD[i] = 0.0f;
    __syncthreads();

    const int c1w = t1 * 128 + wr * 64;
    const int c2w = t2 * 128 + wc * 64;
    const float* A0 = x1 + (size_t)b * HW * CC + (c1w + lo5);
    const float* A1 = A0 + 32;
    const float* B0 = x2 + (size_t)b * HW * CC + (c2w + lo5);
    const float* B1 = B0 + 32;

    f32x16 acc00 = {}, acc01 = {}, acc10 = {}, acc11 = {};
    for (int ks = 0; ks < 12; ++ks) {
        const int kb = ks * 16 + hi * 8;
        bf8 a0, a1, b0v, b1v;
        #pragma unroll
        for (int j = 0; j < 8; ++j) {
            const size_t off = (size_t)(kb + j) * CC;
            a0[j] = (__bf16)A0[off]; a1[j] = (__bf16)A1[off];
            b0v[j] = (__bf16)B0[off]; b1v[j] = (__bf16)B1[off];
        }
        acc00 = __builtin_amdgcn_mfma_f32_32x32x16_bf16(a0, b0v, acc00, 0, 0, 0);
        acc01 = __builtin_amdgcn_mfma_f32_32x32x16_bf16(a0, b1v, acc01, 0, 0, 0);
        acc10 = __builtin_amdgcn_mfma_f32_32x32x16_bf16(a1, b0v, acc10, 0, 0, 0);
        acc11 = __builtin_amdgcn_mfma_f32_32x32x16_bf16(a1, b1v, acc11, 0, 0, 0);
    }
    {
        const int kb = 192 + hi * 8;
        bf8 a0, a1, b0v, b1v;
        #pragma unroll
        for (int j = 0; j < 8; ++j) {
            const int k = kb + j;
            const size_t off = (size_t)k * CC;
            const bool v = (k < HW);
            a0[j]  = (__bf16)(v ? A0[off] : 0.0f);
            a1[j]  = (__bf16)(v ? A1[off] : 0.0f);
            b0v[j] = (__bf16)(v ? B0[off] : 0.0f);
            b1v[j] = (__bf16)(v ? B1[off] : 0.0f);
        }
        acc00 = __builtin_amdgcn_mfma_f32_32x32x16_bf16(a0, b0v, acc00, 0, 0, 0);
        acc01 = __builtin_amdgcn_mfma_f32_32x32x16_bf16(a0, b1v, acc01, 0, 0, 0);
        acc10 = __builtin_amdgcn_mfma_f32_32x32x16_bf16(a1, b0v, acc10, 0, 0, 0);
        acc11 = __builtin_amdgcn_mfma_f32_32x32x16_bf16(a1, b1v, acc11, 0, 0, 0);
    }

    const float s2v0 = s2[c2w + lo5];
    const float s2v1 = s2[c2w + 32 + lo5];
    const int   h2v0 = h2[c2w + lo5];
    const int   h2v1 = h2[c2w + 32 + lo5];
    #pragma unroll
    for (int rt = 0; rt < 2; ++rt) {
        const f32x16 accL = rt ? acc10 : acc00;
        const f32x16 accR = rt ? acc11 : acc01;
        #pragma unroll
        for (int reg = 0; reg < 16; ++reg) {
            const int c1 = c1w + rt * 32 + (reg & 3) + 8 * (reg >> 2) + 4 * hi;
            const float sv = s1[c1];
            const int   hv = h1[c1];
            unsafeAtomicAdd(&accD[(hv + h2v0) & (DD - 1)], sv * s2v0 * accL[reg]);
            unsafeAtomicAdd(&accD[(hv + h2v1) & (DD - 1)], sv * s2v1 * accR[reg]);
        }
    }
    __syncthreads();

    if (use_ws) {
        float4* dst = (float4*)(ws + (size_t)bid * DD);
        const float4* src = (const float4*)accD;
        #pragma unroll
        for (int i = 0; i < DD / 4 / NTHR; ++i)
            dst[tid + i * NTHR] = src[tid + i * NTHR];
    } else {
        float* ob = out + (size_t)b * DD;
        for (int i = tid; i < DD; i += NTHR)
            atomicAdd(&ob[i], accD[i]);
    }
}

extern "C" void kernel_launch(void* const* d_in, const int* in_sizes, int n_in,
                              void* d_out, int out_size, void* d_ws, size_t ws_size,
                              hipStream_t stream) {
    const float* x1 = (const float*)d_in[0];
    const float* x2 = (const float*)d_in[1];
    const float* s1 = (const float*)d_in[2];
    const float* s2 = (const float*)d_in[3];
    const int*   h1 = (const int*)d_in[4];
    const int*   h2 = (const int*)d_in[5];
    float* out = (float*)d_out;

    dim3 block(NTHR);
    if (ws_size >= NEED_FUSED) {
        __bf16* xT1   = (__bf16*)d_ws;
        __bf16* xT2   = xT1 + XT_ELEMS;
        float*  parts = (float*)((char*)d_ws + 2 * XT_BYTES);
        cbp_transpose_kernel<<<dim3(NB * 32), block, 0, stream>>>(
            x1, x2, s1, s2, xT1, xT2);
        cbp_gram_scatter_kernel<<<dim3(NB * TILES_PER_B), block, 0, stream>>>(
            xT1, xT2, h1, h2, parts);
        cbp_reduce_kernel<<<dim3(NB * 8), block, 0, stream>>>(parts, out);
    } else if (ws_size >= NEED_R5) {
        float* parts = (float*)d_ws;
        cbp_mfma_kernel<<<dim3(NB * TILES_PER_B), block, 0, stream>>>(
            x1, x2, s1, s2, h1, h2, parts, out, 1);
        cbp_reduce_kernel<<<dim3(NB * 8), block, 0, stream>>>(parts, out);
    } else {
        hipMemsetAsync(out, 0, (size_t)out_size * sizeof(float), stream);
        cbp_mfma_kernel<<<dim3(NB * TILES_PER_B), block, 0, stream>>>(
            x1, x2, s1, s2, h1, h2, (float*)d_ws, out, 0);
    }
}